// Round 8
// baseline (156.264 us; speedup 1.0000x reference)
//
#include <hip/hip_runtime.h>
#include <math.h>
#include <limits.h>

#define N_SAMPLES 65536
#define N_FRAMES  128
#define NUM_COEFF 6
#define NSEG      126        // N_FRAMES - 2
#define VEC_SIZE  808
#define ZCLAMP    (VEC_SIZE - 7)   // 801

// ---- workspace layout (byte offsets) ----
#define WS_XL    0           // float xl[65536]  (x with tile-initial state 0)
#define WS_PP    262144      // float PP[65536]  (in-tile prefix product of -a)
#define WS_VALS  524288      // float vals8[65536][8]; slot 7 = z (float)
#define WS_TM    2621440     // float TM[64] tile aggregate multiplier
#define WS_TC    2621696     // float TC[64] tile aggregate offset
#define WS_D     2621952     // int: min dependency distance of final system
#define WS_PL    2622464     // 3 SoA planes: float4[65536] each (24 bf16 coeffs)
#define WS_MQ    5768192     // float4[65536] = (X15, ring_idx_f, u12, u13)

// Thomas-algorithm forward coefficients cp[i] = 1/(4 - cp[i-1]) are
// DATA-INDEPENDENT -> compile-time table (bit-identical IEEE f64).
struct CpTab { double v[NSEG]; };
static constexpr CpTab make_cp() {
    CpTab t{};
    t.v[0] = 0.25;
    for (int i = 1; i < NSEG; ++i) t.v[i] = 1.0 / (4.0 - t.v[i - 1]);
    return t;
}
__device__ __constant__ CpTab CP = make_cp();

// ---------------------------------------------------------------------------
// K1: front-end, 320 blocks (R4/R6-verified, unchanged).
// Blocks 0..255: spline -> vals8. Blocks 256..319: exc IIR phase-1 tiles.
// ---------------------------------------------------------------------------
__global__ __launch_bounds__(256) void k_front(
    const float* __restrict__ delay_len,
    const float* __restrict__ raw_gain,
    const float* __restrict__ raw_coeff,
    const float* __restrict__ exc,
    const float* __restrict__ burst,
    float* __restrict__ ws)
{
    const int tid = threadIdx.x;
    const int b = blockIdx.x;

    if (b >= 256) {
        float* xl = ws + WS_XL / 4;
        float* PP = ws + WS_PP / 4;
        float* TM = ws + WS_TM / 4;
        float* TC = ws + WS_TC / 4;
        const int tile = b - 256;
        const int base = tile * 1024 + tid * 4;

        if (tile == 0 && tid == 0) *(int*)((char*)ws + WS_D) = 0x7fffffff;

        const float4 a4 = *(const float4*)(exc + base);
        const float4 b4 = *(const float4*)(burst + base);

        float m = -a4.x,            c = b4.x;
        m = -a4.y * m;              c = b4.y - a4.y * c;
        m = -a4.z * m;              c = b4.z - a4.z * c;
        m = -a4.w * m;              c = b4.w - a4.w * c;

        __shared__ float sm[256], sc[256];
        sm[tid] = m; sc[tid] = c;
        __syncthreads();
        for (int off = 1; off < 256; off <<= 1) {
            const float cm = sm[tid], cc = sc[tid];
            float pm = 1.f, pc = 0.f;
            if (tid >= off) { pm = sm[tid - off]; pc = sc[tid - off]; }
            __syncthreads();
            if (tid >= off) { sm[tid] = cm * pm; sc[tid] = cm * pc + cc; }
            __syncthreads();
        }
        float y = (tid == 0) ? 0.f : sc[tid - 1];
        float P = (tid == 0) ? 1.f : sm[tid - 1];

        float4 x4, p4;
        y = b4.x - a4.x * y;  P = -a4.x * P;  x4.x = y; p4.x = P;
        y = b4.y - a4.y * y;  P = -a4.y * P;  x4.y = y; p4.y = P;
        y = b4.z - a4.z * y;  P = -a4.z * P;  x4.z = y; p4.z = P;
        y = b4.w - a4.w * y;  P = -a4.w * P;  x4.w = y; p4.w = P;

        *(float4*)(xl + base) = x4;
        *(float4*)(PP + base) = p4;
        if (tid == 255) { TM[tile] = sm[255]; TC[tile] = sc[255]; }
        return;
    }

    float* vals8 = ws + WS_VALS / 4;
    __shared__ float Y[7][N_FRAMES];
    __shared__ float M[7][N_FRAMES];
    __shared__ double dp[7][NSEG];

    if (tid < N_FRAMES) {
        float s[NUM_COEFF];
        float sum = 0.f;
        for (int j = 0; j < NUM_COEFF; ++j) {
            s[j] = 1.f / (1.f + expf(-raw_coeff[tid * NUM_COEFF + j]));
            sum += s[j];
        }
        const float gain = 1.f / (1.f + expf(-raw_gain[0]));
        for (int j = 0; j < NUM_COEFF; ++j)
            Y[1 + j][tid] = s[j] / sum * gain;
        Y[0][tid] = delay_len[tid];
    }
    __syncthreads();

    if (tid < 7) {
        const float* y = Y[tid];
        const double inv_h2 = 127.0 * 127.0;
        double prev = 6.0 * ((double)y[2] - 2.0 * (double)y[1] + (double)y[0]) * inv_h2 * 0.25;
        dp[tid][0] = prev;
        for (int i = 1; i < NSEG; ++i) {
            double ri = 6.0 * ((double)y[i + 2] - 2.0 * (double)y[i + 1] + (double)y[i]) * inv_h2;
            prev = (ri - prev) * CP.v[i];
            dp[tid][i] = prev;
        }
        float* Mc = M[tid];
        Mc[0] = 0.f; Mc[N_FRAMES - 1] = 0.f;
        double mi = dp[tid][NSEG - 1];
        Mc[NSEG] = (float)mi;
        for (int i = NSEG - 2; i >= 0; --i) {
            mi = dp[tid][i] - CP.v[i] * mi;
            Mc[i + 1] = (float)mi;
        }
    }
    __syncthreads();

    const int t = b * 256 + tid;
    const float h = 1.0f / 127.0f;
    const float tf = (float)t * (1.0f / 65535.0f);
    int idx = (int)floorf(tf * 127.0f);
    idx = min(max(idx, 0), 126);
    const float s = tf - (float)idx * h;
    const float s2 = s * s;
    const float s3 = s2 * s;

    float o[7];
#pragma unroll
    for (int c = 0; c < 7; ++c) {
        const float yi  = Y[c][idx];
        const float yi1 = Y[c][idx + 1];
        const float Mi  = M[c][idx];
        const float Mi1 = M[c][idx + 1];
        const float bb = (yi1 - yi) / h - h * (2.f * Mi + Mi1) / 6.f;
        o[c] = yi + bb * s + 0.5f * Mi * s2 + (Mi1 - Mi) * s3 / (6.f * h);
    }
    const float delay = o[0];
    int z = (int)floorf(delay);
    const float alfa = delay - (float)z;
    z = min(max(z, 0), ZCLAMP);

    float v[8];
    v[0] = -((1.f - alfa) * o[1]);
#pragma unroll
    for (int j = 1; j <= 5; ++j)
        v[j] = -(alfa * o[j] + (1.f - alfa) * o[j + 1]);
    v[6] = -(alfa * o[6]);
    v[7] = (float)z;

    float4* vp = (float4*)(vals8 + (size_t)t * 8);
    vp[0] = make_float4(v[0], v[1], v[2], v[3]);
    vp[1] = make_float4(v[4], v[5], v[6], v[7]);
}

// bf16 RNE pack helpers
__device__ __forceinline__ unsigned int bf16_hi(float f) {
    unsigned int b = __float_as_uint(f);
    b = b + 0x7fffu + ((b >> 16) & 1u);
    return b & 0xffff0000u;
}
__device__ __forceinline__ unsigned int bf16_lo(float f) {
    unsigned int b = __float_as_uint(f);
    b = b + 0x7fffu + ((b >> 16) & 1u);
    return b >> 16;
}

// ---------------------------------------------------------------------------
// K2: fused L1 + L1.5 expansion (parallel, 256 blocks) — R4/R6-verified,
// unchanged.
// ---------------------------------------------------------------------------
__global__ __launch_bounds__(256) void k_exp(float* __restrict__ ws)
{
    __shared__ float accL[256 * 33];
    __shared__ float xwin[1920];
    __shared__ float yin[64];
    __shared__ int dmin;
    const int tid = threadIdx.x;
    const int T0 = blockIdx.x * 256;
    const int t = T0 + tid;
    const int wlo = T0 - 1664;

    const float* xl = ws + WS_XL / 4;
    const float* PP = ws + WS_PP / 4;
    const float* vals8 = ws + WS_VALS / 4;
    const float* TM = ws + WS_TM / 4;
    const float* TC = ws + WS_TC / 4;
    float4* PL = (float4*)((char*)ws + WS_PL);
    float4* MQ = (float4*)((char*)ws + WS_MQ);
    int* D = (int*)((char*)ws + WS_D);

    float* acc = accL + tid * 33;
#pragma unroll
    for (int o = 0; o < 32; ++o) acc[o] = 0.f;

    if (tid == 0) dmin = 0x7fffffff;
    if (tid < 64) {
        float m = TM[tid], c = TC[tid];
#pragma unroll
        for (int off = 1; off < 64; off <<= 1) {
            const float pm = __shfl_up(m, off, 64);
            const float pc = __shfl_up(c, off, 64);
            if (tid >= off) { c = fmaf(m, pc, c); m *= pm; }
        }
        const float yp = __shfl_up(c, 1, 64);
        yin[tid] = (tid == 0) ? 0.f : yp;
    }
    __syncthreads();

    for (int i = tid; i < 1920; i += 256) {
        const int p = wlo + i;
        float xv = 0.f;
        if (p >= 0 && p < N_SAMPLES)
            xv = xl[p] + PP[p] * yin[p >> 10];
        xwin[i] = xv;
    }
    __syncthreads();

#define XREAD(p) xwin[(p) - wlo]

    const float4* vp = (const float4*)(vals8 + (size_t)t * 8);
    const float4 r0 = vp[0], r1 = vp[1];
    const float vj[7] = {r0.x, r0.y, r0.z, r0.w, r1.x, r1.y, r1.z};
    const int m0 = t - 1 - (int)r1.w;
    float X1 = XREAD(t);

    float4 s0[7], s1[7];
    float xs[7];
    int sm0[7];
    bool val[7];
    int pmin = INT_MAX;
#pragma unroll
    for (int j = 0; j < 7; ++j) {
        const int s = m0 - j;
        val[j] = (s >= 0);
        const int si = val[j] ? s : 0;
        const float4* sp = (const float4*)(vals8 + (size_t)si * 8);
        s0[j] = sp[0]; s1[j] = sp[1];
        xs[j] = XREAD(val[j] ? s : t);
        sm0[j] = s - 1 - (int)s1[j].w;
        if (val[j]) pmin = min(pmin, sm0[j]);
    }
    if (pmin == INT_MAX) pmin = t - 900;
    const int B1 = (pmin - 6) & ~3;

#pragma unroll
    for (int j = 0; j < 7; ++j) {
        if (!val[j]) continue;
        X1 -= vj[j] * xs[j];
        const float sv[7] = {s0[j].x, s0[j].y, s0[j].z, s0[j].w,
                             s1[j].x, s1[j].y, s1[j].z};
        const int ob = sm0[j] - B1;
#pragma unroll
        for (int k = 0; k < 7; ++k) {
            int o = ob - k;
            o = min(max(o, 0), 31);
            acc[o] += vj[j] * sv[k];
        }
    }

    float c1f[32];
#pragma unroll
    for (int o = 0; o < 32; ++o) { c1f[o] = acc[o]; acc[o] = 0.f; }

    float X15 = X1;
    int first = -1;
#pragma unroll
    for (int o = 0; o < 32; ++o)
        if (first < 0 && c1f[o] != 0.f && (B1 + o) >= 0) first = o;

    int B2 = 0, maxq = INT_MIN;
    if (first >= 0) {
        const int pf = B1 + first;
        const float zf = ((const float4*)(vals8 + (size_t)pf * 8))[1].w;
        B2 = ((pf - 1 - (int)zf) - 6) & ~3;

#pragma unroll
        for (int o = 0; o < 32; ++o) {
            const float co = c1f[o];
            const int p = B1 + o;
            if (co == 0.f || p < 0) continue;
            const float4* pv = (const float4*)(vals8 + (size_t)p * 8);
            const float4 v0 = pv[0], v1 = pv[1];
            X15 += co * XREAD(p);
            const int rp = p - 1 - (int)v1.w;
            maxq = max(maxq, rp);
            const float sv[7] = {v0.x, v0.y, v0.z, v0.w, v1.x, v1.y, v1.z};
            const int ob = rp - B2;
#pragma unroll
            for (int j = 0; j < 7; ++j) {
                int oo = ob - j;
                oo = min(max(oo, 0), 27);   // band fits in [0,27]
                acc[oo] -= co * sv[j];
            }
        }
    }
#undef XREAD

    // dot2-ordered pack: lo = even coeff, hi = odd coeff
    unsigned int u[14];
#pragma unroll
    for (int i = 0; i < 14; ++i)
        u[i] = bf16_lo(acc[2 * i]) | (bf16_lo(acc[2 * i + 1]) << 16);

    PL[t]             = make_float4(__uint_as_float(u[0]),  __uint_as_float(u[1]),
                                    __uint_as_float(u[2]),  __uint_as_float(u[3]));
    PL[t + 65536]     = make_float4(__uint_as_float(u[4]),  __uint_as_float(u[5]),
                                    __uint_as_float(u[6]),  __uint_as_float(u[7]));
    PL[t + 2 * 65536] = make_float4(__uint_as_float(u[8]),  __uint_as_float(u[9]),
                                    __uint_as_float(u[10]), __uint_as_float(u[11]));
    MQ[t] = make_float4(X15, (float)(B2 & 2047),
                        __uint_as_float(u[12]), __uint_as_float(u[13]));

    if (first >= 0 && maxq > INT_MIN) atomicMin(&dmin, t - maxq);
    __syncthreads();
    if (tid == 0) atomicMin(D, dmin);
}

// lgkm-only workgroup barrier (global loads/stores stay in flight)
__device__ __forceinline__ void bar_lgkm() {
    asm volatile("s_waitcnt lgkmcnt(0)\n\ts_barrier" ::: "memory");
}

// native vector types for inline-asm "v"/"s" constraints
typedef float f32x4 __attribute__((ext_vector_type(4)));
typedef unsigned int u32;
typedef u32 u32x4v __attribute__((ext_vector_type(4)));

// 128-bit buffer resource descriptor (SRSRC): base[47:0], stride=0,
// num_records=BYTES, word3=raw-dword. OOB stores are dropped.
__device__ __forceinline__ u32x4v make_srsrc(const void* p, u32 bytes) {
    unsigned long long a = (unsigned long long)p;
    u32x4v r;
    r.x = (u32)a;
    r.y = (u32)(a >> 32);
    r.z = bytes;
    r.w = 0x00020000u;
    return r;
}

// buffer load dwordx4: one 32-bit voffset, loop-invariant SGPR descriptor.
// Volatile asm: pinned at issue site, invisible to SIInsertWaitcnts ->
// no implicit vmcnt drain; we wait manually with VWAIT8.
#define BLD4(dst, voff, srsrc)                                                 \
    asm volatile("buffer_load_dwordx4 %0, %1, %2, 0 offen"                     \
        : "=v"(dst) : "v"(voff), "s"(srsrc))

// Counted wait (proof as R6): at set k's wait, sets k+1 and k+2 (8 loads)
// are always newer, plus 0..3 stores -> vmcnt(8) guarantees set k retired.
// Tied "+v" operands make all uses data-dependent on this asm.
#define VWAIT8(a, b, c, d)                                                     \
    asm volatile("s_waitcnt vmcnt(8)"                                          \
        : "+v"(a), "+v"(b), "+v"(c), "+v"(d))

// packed bf16x2 dot product: d = a.lo*b.lo + a.hi*b.hi + d  (f32 accum)
#define DOT2BF(acc_, a_, b_)                                                   \
    asm("v_dot2_f32_bf16 %0, %1, %2, %0" : "+v"(acc_) : "v"(a_), "v"(b_))

// ---------------------------------------------------------------------------
// K3: sequential chunked recurrence — R8 bisection pass.
// R7 FAILED (absmax 0.107 vs 0.0234): one of its 5 changes silently alters
// data. This round keeps {SRSRC loads, buffer_store, tail peel, voffset
// arithmetic} and REVERTS the prime suspect — the hand-rolled
// ds_read2_b64 train + manual lgkmcnt(0) — to R6's verified C++ tap reads.
// To also eliminate the OOB-returns-0 suspect, the voffset is CLAMPED to
// row 65535 (one v_min_u32 per PRE), so every load touches exactly the row
// R6's clamped flat loads touched -> loaded values bit-identical to R6.
// Verdict protocol: pass (absmax exactly 0.0234375) => R7 bug was the asm
// DS train; fail => bug in SRSRC group, revert fully next round.
// ---------------------------------------------------------------------------
__global__ __launch_bounds__(320, 1) void k_ks3(
    const float* __restrict__ ws_c,
    float* __restrict__ out)
{
    __shared__ __align__(16) unsigned short ringb[2080];   // 2048 + 32 pad
    const int tid = threadIdx.x;
    const int* Dp = (const int*)((const char*)ws_c + WS_D);

    for (int i = tid; i < 2080; i += 320) ringb[i] = 0;
    __syncthreads();

    int C = *Dp;
    if (C > 320) C = 320;   // one sample per lane, 5 waves
    if (C < 1) C = 1;
    const int C4 = 4 * C;

    const u32x4v srPL0 = make_srsrc((const char*)ws_c + WS_PL,           65536u * 16u);
    const u32x4v srPL1 = make_srsrc((const char*)ws_c + WS_PL + 1048576, 65536u * 16u);
    const u32x4v srPL2 = make_srsrc((const char*)ws_c + WS_PL + 2097152, 65536u * 16u);
    const u32x4v srMQ  = make_srsrc((const char*)ws_c + WS_MQ,           65536u * 16u);
    const u32x4v srOUT = make_srsrc(out,                                 65536u * 4u);

    const u32 s16 = (u32)C4 * 16u;          // voffset advance per own step
    const u32 VMAX = 65535u * 16u;          // clamp: same row R6 clamped to
    u32 vA = (u32)tid * 16u;
    u32 vB = vA + (u32)C * 16u;
    u32 vU = vA + (u32)(2 * C) * 16u;
    u32 vV = vA - (u32)C * 16u;             // wraps; first advance lands at 3C

#define PRE(P0, P1, P2, PM, VOFF)                                              \
    do {                                                                       \
        const u32 vo_ = (VOFF) < VMAX ? (VOFF) : VMAX;                         \
        BLD4(P0, vo_, srPL0); BLD4(P1, vo_, srPL1);                            \
        BLD4(P2, vo_, srPL2); BLD4(PM, vo_, srMQ);                             \
    } while (0)

// R6-verified DOT: compiler-scheduled ds_read_b64 x7 + dot2 chain.
#define DOT(P0, P1, P2, PM, YOUT)                                              \
    do {                                                                       \
        const int idx_ = (int)(PM).y;                                          \
        const unsigned int u_[14] = {                                          \
            __float_as_uint((P0).x), __float_as_uint((P0).y),                  \
            __float_as_uint((P0).z), __float_as_uint((P0).w),                  \
            __float_as_uint((P1).x), __float_as_uint((P1).y),                  \
            __float_as_uint((P1).z), __float_as_uint((P1).w),                  \
            __float_as_uint((P2).x), __float_as_uint((P2).y),                  \
            __float_as_uint((P2).z), __float_as_uint((P2).w),                  \
            __float_as_uint((PM).z), __float_as_uint((PM).w)};                 \
        float p0 = 0.f, p1 = 0.f;                                              \
        _Pragma("unroll")                                                      \
        for (int q = 0; q < 7; ++q) {                                          \
            const uint2 rr_ = *(const uint2*)&ringb[idx_ + 4 * q];             \
            DOT2BF(p0, u_[2 * q],     rr_.x);                                  \
            DOT2BF(p1, u_[2 * q + 1], rr_.y);                                  \
        }                                                                      \
        YOUT = (PM).x + (p0 + p1);                                             \
    } while (0)

// Full-range step: only the tid<C guard (t0 < N_SAMPLES guaranteed).
#define STEPF(P0, P1, P2, PM, N0, N1, N2, NM, VN, S_)                          \
    do {                                                                       \
        VWAIT8(P0, P1, P2, PM);                                                \
        VN += s16;                                                             \
        PRE(N0, N1, N2, NM, VN);                                               \
        if (tid < C) {                                                         \
            const int t0 = (S_) + tid;                                         \
            float y0; DOT(P0, P1, P2, PM, y0);                                 \
            const int w = t0 & 2047;                                           \
            const unsigned short yb = (unsigned short)bf16_lo(y0);             \
            ringb[w] = yb;                                                     \
            if (w < 32) ringb[w + 2048] = yb;                                  \
            asm volatile("buffer_store_dword %0, %1, %2, 0 offen"              \
                :: "v"(y0), "v"((u32)(t0 * 4)), "s"(srOUT));                   \
        }                                                                      \
        bar_lgkm();                                                            \
    } while (0)

// Tail step: adds the t0 < N_SAMPLES guard.
#define STEPT(P0, P1, P2, PM, N0, N1, N2, NM, VN, S_)                          \
    do {                                                                       \
        VWAIT8(P0, P1, P2, PM);                                                \
        VN += s16;                                                             \
        PRE(N0, N1, N2, NM, VN);                                               \
        const int t0 = (S_) + tid;                                             \
        if (tid < C && t0 < N_SAMPLES) {                                       \
            float y0; DOT(P0, P1, P2, PM, y0);                                 \
            const int w = t0 & 2047;                                           \
            const unsigned short yb = (unsigned short)bf16_lo(y0);             \
            ringb[w] = yb;                                                     \
            if (w < 32) ringb[w + 2048] = yb;                                  \
            asm volatile("buffer_store_dword %0, %1, %2, 0 offen"              \
                :: "v"(y0), "v"((u32)(t0 * 4)), "s"(srOUT));                   \
        }                                                                      \
        bar_lgkm();                                                            \
    } while (0)

    f32x4 A0, A1, A2, AM;
    f32x4 B0, B1, B2, BM;
    f32x4 U0, U1, U2, UM;
    f32x4 V0, V1, V2, VM;

    PRE(A0, A1, A2, AM, vA);
    PRE(B0, B1, B2, BM, vB);
    PRE(U0, U1, U2, UM, vU);

    int S = 0;
    for (; S + C4 <= N_SAMPLES; S += C4) {
        STEPF(A0, A1, A2, AM, V0, V1, V2, VM, vV, S);
        STEPF(B0, B1, B2, BM, A0, A1, A2, AM, vA, S + C);
        STEPF(U0, U1, U2, UM, B0, B1, B2, BM, vB, S + 2 * C);
        STEPF(V0, V1, V2, VM, U0, U1, U2, UM, vU, S + 3 * C);
    }
    if (S < N_SAMPLES) {
        STEPT(A0, A1, A2, AM, V0, V1, V2, VM, vV, S);
        STEPT(B0, B1, B2, BM, A0, A1, A2, AM, vA, S + C);
        STEPT(U0, U1, U2, UM, B0, B1, B2, BM, vB, S + 2 * C);
        STEPT(V0, V1, V2, VM, U0, U1, U2, UM, vU, S + 3 * C);
    }
#undef STEPF
#undef STEPT
#undef DOT
#undef PRE
}

// ---------------------------------------------------------------------------
extern "C" void kernel_launch(void* const* d_in, const int* in_sizes, int n_in,
                              void* d_out, int out_size, void* d_ws, size_t ws_size,
                              hipStream_t stream)
{
    const float* delay_len = (const float*)d_in[0];
    const float* raw_gain  = (const float*)d_in[1];
    const float* raw_coeff = (const float*)d_in[2];
    const float* exc       = (const float*)d_in[3];
    const float* burst     = (const float*)d_in[4];
    float* ws  = (float*)d_ws;
    float* out = (float*)d_out;

    hipLaunchKernelGGL(k_front, dim3(320), dim3(256), 0, stream,
                       delay_len, raw_gain, raw_coeff, exc, burst, ws);
    hipLaunchKernelGGL(k_exp, dim3(256), dim3(256), 0, stream, ws);
    hipLaunchKernelGGL(k_ks3, dim3(1), dim3(320), 0, stream, ws, out);
}